// Round 4
// baseline (255.450 us; speedup 1.0000x reference)
//
#include <hip/hip_runtime.h>

// Problem constants (x: (16,3,512,512) f32, PATCH=16, STRIDE=8, k=8)
#define BB      16
#define CH      3
#define HH      512
#define WW      512
#define NH      63
#define NW      63
#define NN      3969            // NH*NW
#define FDIM    768             // CH*16*16
#define EDGES   31752           // NN*8

#define PATCHES_ELEMS  (BB * NN * FDIM)   // 48771072
#define POS_ELEMS      (BB * NN * 2)      // 127008

#define F4        (FDIM / 4)              // 192 float4 per (b,n)
#define TOTAL_G   (BB * NN * F4)          // 12192768 float4s
#define PBLOCKS   3969                    // patch blocks
#define PTHREADS  (PBLOCKS * 256)         // 1016064
#define ITER      12                      // PTHREADS * ITER == TOTAL_G exactly

#define PE_THREADS (BB * NN)              // 63504
#define PE_BLOCKS  ((PE_THREADS + 255) / 256)  // 249

typedef float  f4 __attribute__((ext_vector_type(4)));
typedef float  f2 __attribute__((ext_vector_type(2)));

// ---------------------------------------------------------------------------
// One fused kernel.
//  blocks [0, PE_BLOCKS): one thread per (b,n) -> positions + 8-NN edges.
//    (Placed first so they overlap the patch stream instead of tailing it.)
//  blocks [PE_BLOCKS, +PBLOCKS): patches gather, grid-stride x12 fully
//    unrolled -> 12 independent 16B load/store pairs in flight per thread
//    (ILP latency hiding + 12x fewer block dispatches). Lanes stay
//    consecutive in g, so each wave store covers 1KB contiguous -> full
//    64B lines -> nontemporal stores are RMW-free and keep 195MB of
//    streaming writes out of the caches.
// ---------------------------------------------------------------------------
__global__ __launch_bounds__(256) void fused_kernel(const float* __restrict__ x,
                                                    float* __restrict__ out) {
    unsigned bid = blockIdx.x;

    if (bid >= PE_BLOCKS) {
        unsigned tid = (bid - PE_BLOCKS) * 256u + threadIdx.x;  // [0, PTHREADS)
#pragma unroll
        for (unsigned k = 0; k < ITER; ++k) {
            unsigned g    = tid + k * PTHREADS;   // [0, TOTAL_G), exact
            unsigned f4i  = g % F4;
            unsigned rest = g / F4;
            unsigned n    = rest % NN;
            unsigned b    = rest / NN;

            unsigned f  = f4i << 2;             // first feature of the 4
            unsigned c  = f >> 8;               // / 256
            unsigned di = (f >> 4) & 15;
            unsigned dj = f & 15;               // multiple of 4
            unsigned i  = n / NW;
            unsigned j  = n - i * NW;

            const f4 v = *reinterpret_cast<const f4*>(
                x + ((size_t)((b * CH + c) * HH + i * 8u + di) * WW + j * 8u + dj));
            __builtin_nontemporal_store(v, reinterpret_cast<f4*>(out + (size_t)g * 4));
        }
    } else {
        unsigned g = bid * 256u + threadIdx.x;
        if (g >= PE_THREADS) return;
        unsigned n = g % NN;                // lanes contiguous in n
        unsigned b = g / NN;
        int i = (int)(n / NW);
        int j = (int)(n - (unsigned)i * NW);

        // positions
        *reinterpret_cast<f2*>(out + PATCHES_ELEMS + (size_t)(b * NN + n) * 2) =
            f2{(float)i, (float)j};

        // 8-NN on the 63x63 grid: the 9 best (incl. self) of top_k(-d2, 9)
        // always lie in the clipped 5x5 window; key = (d2<<12)|idx reproduces
        // top_k's exact ordering (ties -> lower index).
        unsigned best[9];
#pragma unroll
        for (int s = 0; s < 9; ++s) best[s] = 0xFFFFFFFFu;
        for (int di = -2; di <= 2; ++di) {
            int ni = i + di;
            if (ni < 0 || ni >= NH) continue;
            for (int dj = -2; dj <= 2; ++dj) {
                int nj = j + dj;
                if (nj < 0 || nj >= NW) continue;
                unsigned key = ((unsigned)(di * di + dj * dj) << 12)
                             | (unsigned)(ni * NW + nj);
#pragma unroll
                for (int s = 0; s < 9; ++s) {
                    if (key < best[s]) { unsigned tmp = best[s]; best[s] = key; key = tmp; }
                }
            }
        }

        float src_f = (float)n;
        f4 s4 = {src_f, src_f, src_f, src_f};
        f4 t0 = {(float)(best[1] & 0xFFFu), (float)(best[2] & 0xFFFu),
                 (float)(best[3] & 0xFFFu), (float)(best[4] & 0xFFFu)};
        f4 t1 = {(float)(best[5] & 0xFFFu), (float)(best[6] & 0xFFFu),
                 (float)(best[7] & 0xFFFu), (float)(best[8] & 0xFFFu)};

        float* ebase = out + PATCHES_ELEMS + POS_ELEMS + (size_t)b * 2 * EDGES;
        *reinterpret_cast<f4*>(ebase + (size_t)n * 8)             = s4;
        *reinterpret_cast<f4*>(ebase + (size_t)n * 8 + 4)         = s4;
        *reinterpret_cast<f4*>(ebase + EDGES + (size_t)n * 8)     = t0;
        *reinterpret_cast<f4*>(ebase + EDGES + (size_t)n * 8 + 4) = t1;
    }
}

extern "C" void kernel_launch(void* const* d_in, const int* in_sizes, int n_in,
                              void* d_out, int out_size, void* d_ws, size_t ws_size,
                              hipStream_t stream) {
    const float* x = (const float*)d_in[0];
    float* out     = (float*)d_out;
    fused_kernel<<<PE_BLOCKS + PBLOCKS, 256, 0, stream>>>(x, out);
}

// Round 5
// 238.850 us; speedup vs baseline: 1.0695x; 1.0695x over previous
//
#include <hip/hip_runtime.h>

// Problem constants (x: (16,3,512,512) f32, PATCH=16, STRIDE=8, k=8)
#define BB      16
#define CH      3
#define HH      512
#define WW      512
#define NH      63
#define NW      63
#define NN      3969            // NH*NW
#define FDIM    768             // CH*16*16
#define EDGES   31752           // NN*8

#define PATCHES_ELEMS  (BB * NN * FDIM)   // 48771072
#define POS_ELEMS      (BB * NN * 2)      // 127008

#define PE_THREADS (BB * NN)                   // 63504
#define PE_BLOCKS  ((PE_THREADS + 255) / 256)  // 249
#define PATCH_BLOCKS (BB * NH)                 // 1008: one block per (b, i)

#define PADW 516                               // LDS row pad: <=2-way banks

typedef float  f4 __attribute__((ext_vector_type(4)));
typedef float  f2 __attribute__((ext_vector_type(2)));

// ---------------------------------------------------------------------------
// Fused kernel, LDS-staged patch gather.
//  blocks [0, PE_BLOCKS): one thread per (b,n) -> positions + 8-NN edges.
//  blocks [PE_BLOCKS, +PATCH_BLOCKS): block = one (b, i). For each channel:
//    stage the 16 input rows (i*8..i*8+15, 512 cols) into LDS via fully
//    contiguous 4KB/wave-instr loads (reads are now long HBM runs, each row
//    fetched by <=2 blocks), then write the 63 patches' 256-float c-slices:
//    each wave-instr = 64 lanes x 16B = 1KB contiguous nt store (full lines,
//    no RMW, bypasses L2 so the input stays cache-resident).
// ---------------------------------------------------------------------------
__global__ __launch_bounds__(256) void fused_kernel(const float* __restrict__ x,
                                                    float* __restrict__ out) {
    unsigned bid = blockIdx.x;

    if (bid >= PE_BLOCKS) {
        unsigned pb = bid - PE_BLOCKS;      // [0, 1008)
        unsigned b  = pb / NH;
        unsigned i  = pb % NH;
        unsigned tid = threadIdx.x;

        __shared__ float lds[16][PADW];

        unsigned lane = tid & 63u;
        unsigned wave = tid >> 6;           // 0..3
        unsigned dio  = lane >> 2;          // di for the write phase, 0..15
        unsigned q4   = (lane & 3u) << 2;   // dj offset 0,4,8,12

        for (unsigned c = 0; c < CH; ++c) {
            const float* base = x + ((size_t)(b * CH + c) * HH + i * 8u) * WW;
            // stage 16 rows x 512 cols = 2048 float4s, 8 per thread
#pragma unroll
            for (unsigned u = 0; u < 8; ++u) {
                unsigned f4id = u * 256u + tid;        // [0, 2048)
                unsigned di   = f4id >> 7;             // 0..15
                unsigned col  = (f4id & 127u) << 2;    // 0..508
                *reinterpret_cast<f4*>(&lds[di][col]) =
                    *reinterpret_cast<const f4*>(base + (size_t)di * WW + col);
            }
            __syncthreads();

            // 63 patches; wave w handles j = w, w+4, ...
            for (unsigned j = wave; j < NW; j += 4) {
                const f4 v = *reinterpret_cast<const f4*>(&lds[dio][j * 8u + q4]);
                float* dst = out + ((size_t)(b * NN + i * NW + j) * FDIM
                                    + c * 256u + (lane << 2));
                __builtin_nontemporal_store(v, reinterpret_cast<f4*>(dst));
            }
            __syncthreads();
        }
    } else {
        unsigned g = bid * 256u + threadIdx.x;
        if (g >= PE_THREADS) return;
        unsigned n = g % NN;                // lanes contiguous in n
        unsigned b = g / NN;
        int i = (int)(n / NW);
        int j = (int)(n - (unsigned)i * NW);

        // positions
        *reinterpret_cast<f2*>(out + PATCHES_ELEMS + (size_t)(b * NN + n) * 2) =
            f2{(float)i, (float)j};

        // 8-NN on the 63x63 grid: the 9 best (incl. self) of top_k(-d2, 9)
        // always lie in the clipped 5x5 window; key = (d2<<12)|idx reproduces
        // top_k's exact ordering (ties -> lower index).
        unsigned best[9];
#pragma unroll
        for (int s = 0; s < 9; ++s) best[s] = 0xFFFFFFFFu;
        for (int di = -2; di <= 2; ++di) {
            int ni = i + di;
            if (ni < 0 || ni >= NH) continue;
            for (int dj = -2; dj <= 2; ++dj) {
                int nj = j + dj;
                if (nj < 0 || nj >= NW) continue;
                unsigned key = ((unsigned)(di * di + dj * dj) << 12)
                             | (unsigned)(ni * NW + nj);
#pragma unroll
                for (int s = 0; s < 9; ++s) {
                    if (key < best[s]) { unsigned tmp = best[s]; best[s] = key; key = tmp; }
                }
            }
        }

        float src_f = (float)n;
        f4 s4 = {src_f, src_f, src_f, src_f};
        f4 t0 = {(float)(best[1] & 0xFFFu), (float)(best[2] & 0xFFFu),
                 (float)(best[3] & 0xFFFu), (float)(best[4] & 0xFFFu)};
        f4 t1 = {(float)(best[5] & 0xFFFu), (float)(best[6] & 0xFFFu),
                 (float)(best[7] & 0xFFFu), (float)(best[8] & 0xFFFu)};

        float* ebase = out + PATCHES_ELEMS + POS_ELEMS + (size_t)b * 2 * EDGES;
        *reinterpret_cast<f4*>(ebase + (size_t)n * 8)             = s4;
        *reinterpret_cast<f4*>(ebase + (size_t)n * 8 + 4)         = s4;
        *reinterpret_cast<f4*>(ebase + EDGES + (size_t)n * 8)     = t0;
        *reinterpret_cast<f4*>(ebase + EDGES + (size_t)n * 8 + 4) = t1;
    }
}

extern "C" void kernel_launch(void* const* d_in, const int* in_sizes, int n_in,
                              void* d_out, int out_size, void* d_ws, size_t ws_size,
                              hipStream_t stream) {
    const float* x = (const float*)d_in[0];
    float* out     = (float*)d_out;
    fused_kernel<<<PE_BLOCKS + PATCH_BLOCKS, 256, 0, stream>>>(x, out);
}

// Round 6
// 232.695 us; speedup vs baseline: 1.0978x; 1.0265x over previous
//
#include <hip/hip_runtime.h>

// Problem constants (x: (16,3,512,512) f32, PATCH=16, STRIDE=8, k=8)
#define BB      16
#define CH      3
#define HH      512
#define WW      512
#define NH      63
#define NW      63
#define NN      3969            // NH*NW
#define FDIM    768             // CH*16*16
#define EDGES   31752           // NN*8

#define PATCHES_ELEMS  (BB * NN * FDIM)   // 48771072
#define POS_ELEMS      (BB * NN * 2)      // 127008

#define PE_THREADS   (BB * NN)                   // 63504
#define PE_BLOCKS    ((PE_THREADS + 255) / 256)  // 249
#define PATCH_BLOCKS (BB * NH * CH)              // 3024: one block per (b,i,c)

typedef float  f4 __attribute__((ext_vector_type(4)));
typedef float  f2 __attribute__((ext_vector_type(2)));

// ---------------------------------------------------------------------------
// Fused kernel.
//  blocks [0, PE_BLOCKS): one thread per (b,n) -> positions + 8-NN edges.
//  blocks [PE_BLOCKS, +PATCH_BLOCKS): block = one (b, i, c).
//    Stage: rows i*8..i*8+15 of channel c are 16 ADJACENT full-width rows =
//    one contiguous 32KB region -> LDS dest is exactly linear per wave ->
//    async __builtin_amdgcn_global_load_lds(16B) direct-to-LDS DMA (no VGPR
//    round-trip, no address VALU). 32KB LDS, unpadded (required for linear
//    dest); 5 blocks/CU so neighbor blocks' store phases hide the stage.
//    Write: per wave-instr, 64 lanes x 16B = 1KB contiguous nt store (full
//    64B lines, no RMW, L2 stays clean for input reads).
// ---------------------------------------------------------------------------
__global__ __launch_bounds__(256) void fused_kernel(const float* __restrict__ x,
                                                    float* __restrict__ out) {
    unsigned bid = blockIdx.x;

    if (bid >= PE_BLOCKS) {
        unsigned pb = bid - PE_BLOCKS;      // [0, 3024)
        unsigned c  = pb % CH;
        unsigned bi = pb / CH;
        unsigned i  = bi % NH;
        unsigned b  = bi / NH;
        unsigned tid = threadIdx.x;

        __shared__ float lds[16 * 512];     // 32 KB, linear (row di = 512 floats)

        const float* base = x + ((size_t)(b * CH + c) * HH + i * 8u) * WW;

        // async stage: 8 x global_load_lds(16B) per thread, linear LDS dest
        typedef const __attribute__((address_space(1))) void* gas_p;
        typedef __attribute__((address_space(3))) void*       las_p;
#pragma unroll
        for (unsigned u = 0; u < 8; ++u) {
            unsigned f4id = u * 256u + tid;            // [0, 2048)
            __builtin_amdgcn_global_load_lds((gas_p)(const void*)(base + f4id * 4u),
                                             (las_p)(void*)(lds + f4id * 4u),
                                             16, 0, 0);
        }
        __syncthreads();   // compiler emits vmcnt(0) drain before barrier

        unsigned lane = tid & 63u;
        unsigned wave = tid >> 6;           // 0..3
        unsigned row  = (lane >> 2) << 9;   // di*512
        unsigned coff = (lane & 3u) << 2;   // dj offset 0,4,8,12
        float* obase = out + ((size_t)(b * NN + i * NW) * FDIM) + c * 256u + (lane << 2);

#pragma unroll
        for (unsigned jj = 0; jj < 16; ++jj) {
            unsigned j = jj * 4u + wave;    // wave-strided patches
            if (j < NW) {
                const f4 v = *reinterpret_cast<const f4*>(lds + row + j * 8u + coff);
                __builtin_nontemporal_store(
                    v, reinterpret_cast<f4*>(obase + (size_t)j * FDIM));
            }
        }
    } else {
        unsigned g = bid * 256u + threadIdx.x;
        if (g >= PE_THREADS) return;
        unsigned n = g % NN;                // lanes contiguous in n
        unsigned b = g / NN;
        int i = (int)(n / NW);
        int j = (int)(n - (unsigned)i * NW);

        // positions
        *reinterpret_cast<f2*>(out + PATCHES_ELEMS + (size_t)(b * NN + n) * 2) =
            f2{(float)i, (float)j};

        // 8-NN on the 63x63 grid: the 9 best (incl. self) of top_k(-d2, 9)
        // always lie in the clipped 5x5 window; key = (d2<<12)|idx reproduces
        // top_k's exact ordering (ties -> lower index).
        unsigned best[9];
#pragma unroll
        for (int s = 0; s < 9; ++s) best[s] = 0xFFFFFFFFu;
        for (int di = -2; di <= 2; ++di) {
            int ni = i + di;
            if (ni < 0 || ni >= NH) continue;
            for (int dj = -2; dj <= 2; ++dj) {
                int nj = j + dj;
                if (nj < 0 || nj >= NW) continue;
                unsigned key = ((unsigned)(di * di + dj * dj) << 12)
                             | (unsigned)(ni * NW + nj);
#pragma unroll
                for (int s = 0; s < 9; ++s) {
                    if (key < best[s]) { unsigned tmp = best[s]; best[s] = key; key = tmp; }
                }
            }
        }

        float src_f = (float)n;
        f4 s4 = {src_f, src_f, src_f, src_f};
        f4 t0 = {(float)(best[1] & 0xFFFu), (float)(best[2] & 0xFFFu),
                 (float)(best[3] & 0xFFFu), (float)(best[4] & 0xFFFu)};
        f4 t1 = {(float)(best[5] & 0xFFFu), (float)(best[6] & 0xFFFu),
                 (float)(best[7] & 0xFFFu), (float)(best[8] & 0xFFFu)};

        float* ebase = out + PATCHES_ELEMS + POS_ELEMS + (size_t)b * 2 * EDGES;
        *reinterpret_cast<f4*>(ebase + (size_t)n * 8)             = s4;
        *reinterpret_cast<f4*>(ebase + (size_t)n * 8 + 4)         = s4;
        *reinterpret_cast<f4*>(ebase + EDGES + (size_t)n * 8)     = t0;
        *reinterpret_cast<f4*>(ebase + EDGES + (size_t)n * 8 + 4) = t1;
    }
}

extern "C" void kernel_launch(void* const* d_in, const int* in_sizes, int n_in,
                              void* d_out, int out_size, void* d_ws, size_t ws_size,
                              hipStream_t stream) {
    const float* x = (const float*)d_in[0];
    float* out     = (float*)d_out;
    fused_kernel<<<PE_BLOCKS + PATCH_BLOCKS, 256, 0, stream>>>(x, out);
}